// Round 4
// baseline (4522.346 us; speedup 1.0000x reference)
//
#include <hip/hip_runtime.h>
#include <stdint.h>
#include <stddef.h>

// Persistent-LSTM, T=1024, B=64, E=H=512 (fp32 in/out).
//
// R5 = R4 (mod-3 sentinel exchange + x prefetch + XCD-pair grouping) with
// three critical-path cuts, protocol unchanged:
//  (a) EARLY POLL ISSUE: the 8 sentinel loads are issued at the very top of
//      the step (before x conversion) — ~1100cy more head start vs R4; the
//      staging barrier's vmcnt drain completes them before the check.
//      Safety: still ordered after step-(t-1) poll success, so the
//      poison≺publish visibility argument is unchanged; a load racing our
//      own publish reads POISON and retries.
//  (b) EARLY PUBLISH: hstage + post-cell barrier deleted. After the exch
//      barrier, wave 0 lanes each own (row pb=lane>>2, cols pc*4..pc*4+3)
//      = exactly one 8B publish chunk: read exch as float4 x4 gates, update
//      4 cells in regs, pack bf16x4, publish immediately; out store is a
//      coalesced float4. Waves 1-3 skip ahead to next-step staging, hiding
//      the publish tail under it.
//  (c) HW bf16 converts in x staging: __bf16 casts (RNE, same numerics as
//      manual f2bf) instead of 4-op bit-twiddle => less VALU before the
//      staging barrier.
//
// Exchange protocol (proven R3/R4):
//  - ws: [4 groups][3 regions][16][512] bf16 = 192KB. Region s%3 holds h_s.
//    8B chunks, relaxed agent-scope atomics, self-validating:
//      fresh := chunk != POISON8 (bf16 +inf x4, |h|<1) && != INIT8 (0xAA).
//  - Producer-side poison one region ahead after poll success; >=1
//    __syncthreads (vmcnt drain) separates poison from publish.
//  - t==1 skips poll + h-MFMA (h_0=0); t==Tn skips publish.
//
// Numerics: weights bf16 hi+lo in regs, x hi/lo split, h single bf16
// => absmax should stay ~0.0039.

#define Tn 1024
#define Bn 64
#define Hn 512
#define En 512
#define NGROUP 4
#define NJBLK 32
#define NBLOCK (NGROUP * NJBLK)
#define POISON8 0x7F807F807F807F80ull
#define INIT8   0xAAAAAAAAAAAAAAAAull

using bf16x8 = __attribute__((ext_vector_type(8))) __bf16;
using f32x4  = __attribute__((ext_vector_type(4))) float;
using u16x8  = __attribute__((ext_vector_type(8))) unsigned short;
using u16x4  = __attribute__((ext_vector_type(4))) unsigned short;

__device__ __forceinline__ unsigned short f2bf(float f) {
    unsigned u = __builtin_bit_cast(unsigned, f);
    unsigned r = (u + 0x7FFFu + ((u >> 16) & 1u)) >> 16;
    return (unsigned short)r;
}
__device__ __forceinline__ float bf2f(unsigned short b) {
    unsigned u = ((unsigned)b) << 16;
    return __builtin_bit_cast(float, u);
}

__global__ __launch_bounds__(256, 1) void lstm_persistent(
    const float* __restrict__ embeds,
    const float* __restrict__ wx0, const float* __restrict__ wh0, const float* __restrict__ bs0,
    const float* __restrict__ wx1, const float* __restrict__ wh1, const float* __restrict__ bs1,
    const float* __restrict__ wx2, const float* __restrict__ wh2, const float* __restrict__ bs2,
    const float* __restrict__ wx3, const float* __restrict__ wh3, const float* __restrict__ bs3,
    float* __restrict__ out, void* __restrict__ ws)
{
    __shared__ unsigned short Xhi[16][520];   // x operand hi, +8 pad
    __shared__ unsigned short Xlo[16][520];   // x operand lo
    __shared__ unsigned short Hl[16][520];    // h operand (bf16)
    __shared__ float exch[4][16][20];         // gate exchange; rows 16B-aligned

    const int tid  = threadIdx.x;
    const int wav  = tid >> 6;     // wave = gate (0=g,1=i,2=f,3=o)
    const int lane = tid & 63;
    const int q    = lane >> 4;
    const int n    = lane & 15;

    // XCD-pair grouping: XCD = blockIdx%8 (round-robin). Group g owns XCDs
    // {2g, 2g+1}; kid is a bijection within the group.
    const int bidx = blockIdx.x;
    const int gid  = (bidx >> 1) & 3;
    const int kid  = ((bidx >> 3) << 1) | (bidx & 1);
    const int b0   = gid * 16;
    const int j0   = kid * 16;

    // ws: [NGROUP][3][2048] qwords; region r holds h_s for s%3==r.
    unsigned long long* gbase = (unsigned long long*)ws + (size_t)gid * 3 * 2048;

    const float* wxp = (wav == 0) ? wx0 : (wav == 1) ? wx1 : (wav == 2) ? wx2 : wx3;
    const float* whp = (wav == 0) ? wh0 : (wav == 1) ? wh1 : (wav == 2) ? wh2 : wh3;
    const float* bsp = (wav == 0) ? bs0 : (wav == 1) ? bs1 : (wav == 2) ? bs2 : bs3;

    // ---- preload weight fragments into registers (bf16 hi/lo) ----
    // B-frag layout for mfma_f32_16x16x32_bf16: lane holds B[k=q*8+i][n]
    bf16x8 WXhi[16], WXlo[16], WHhi[16], WHlo[16];
    const int col = j0 + n;
    #pragma unroll
    for (int kk = 0; kk < 16; ++kk) {
        u16x8 xh, xl, hh, hl;
        #pragma unroll
        for (int i = 0; i < 8; ++i) {
            int k = kk * 32 + q * 8 + i;
            float w  = wxp[(size_t)k * Hn + col];
            unsigned short hi = f2bf(w);
            xh[i] = hi;
            xl[i] = f2bf(w - bf2f(hi));
            w  = whp[(size_t)k * Hn + col];
            hi = f2bf(w);
            hh[i] = hi;
            hl[i] = f2bf(w - bf2f(hi));
        }
        WXhi[kk] = __builtin_bit_cast(bf16x8, xh);
        WXlo[kk] = __builtin_bit_cast(bf16x8, xl);
        WHhi[kk] = __builtin_bit_cast(bf16x8, hh);
        WHlo[kk] = __builtin_bit_cast(bf16x8, hl);
    }
    const float bias_l = bsp[col];

    // wave-0 cell state: lane owns (row pb = lane>>2, cols pc*4 .. pc*4+3)
    const int pb = lane >> 2, pc = lane & 3;
    float c4[4] = {0.f, 0.f, 0.f, 0.f};

    // ---- prologue: prefetch x_0 into registers ----
    float4 xpre[8];
    #pragma unroll
    for (int it = 0; it < 8; ++it) {
        int idx = tid + it * 256;
        int r = idx >> 7, cc = idx & 127;
        xpre[it] = ((const float4*)(embeds + ((size_t)(b0 + r)) * En))[cc];
    }

    for (int t = 1; t <= Tn; ++t) {
        const int tau = t - 1;

        // ---- (a) EARLY poll issue: sentinel loads at the very top ----
        unsigned long long hv8[8];
        unsigned long long* src = gbase + (size_t)((t - 1) % 3) * 2048;
        if (t > 1) {
            #pragma unroll
            for (int i = 0; i < 8; ++i)
                hv8[i] = __hip_atomic_load(src + tid + i * 256,
                                           __ATOMIC_RELAXED, __HIP_MEMORY_SCOPE_AGENT);
        }

        // ---- stage x_tau: registers -> bf16 hi/lo in LDS ----
        #pragma unroll
        for (int it = 0; it < 8; ++it) {
            int idx = tid + it * 256;          // 0..2047
            int r = idx >> 7, cc = idx & 127;  // row(batch), float4 index
            float4 v = xpre[it];
            float fs[4] = {v.x, v.y, v.z, v.w};
            u16x4 vh, vl;
            #pragma unroll
            for (int e = 0; e < 4; ++e) {
                __bf16 hb = (__bf16)fs[e];                    // RNE
                vh[e] = __builtin_bit_cast(unsigned short, hb);
                vl[e] = __builtin_bit_cast(unsigned short,
                                           (__bf16)(fs[e] - (float)hb));
            }
            *(u16x4*)&Xhi[r][cc * 4] = vh;
            *(u16x4*)&Xlo[r][cc * 4] = vl;
        }
        __syncthreads();

        // ---- prefetch x_t (next step) into registers ----
        if (t < Tn) {
            #pragma unroll
            for (int it = 0; it < 8; ++it) {
                int idx = tid + it * 256;
                int r = idx >> 7, cc = idx & 127;
                xpre[it] = ((const float4*)(embeds + ((size_t)t * Bn + b0 + r) * En))[cc];
            }
        }

        f32x4 acc, acc2;
        acc[0] = bias_l; acc[1] = bias_l; acc[2] = bias_l; acc[3] = bias_l;
        acc2[0] = 0.f; acc2[1] = 0.f; acc2[2] = 0.f; acc2[3] = 0.f;

        // ---- x part: (xhi+xlo) @ (Whi+Wlo), dropping lo*lo ----
        #pragma unroll
        for (int kk = 0; kk < 16; ++kk) {
            bf16x8 ah = __builtin_bit_cast(bf16x8, *(const u16x8*)&Xhi[n][kk * 32 + q * 8]);
            bf16x8 al = __builtin_bit_cast(bf16x8, *(const u16x8*)&Xlo[n][kk * 32 + q * 8]);
            acc  = __builtin_amdgcn_mfma_f32_16x16x32_bf16(ah, WXhi[kk], acc, 0, 0, 0);
            acc2 = __builtin_amdgcn_mfma_f32_16x16x32_bf16(ah, WXlo[kk], acc2, 0, 0, 0);
            acc2 = __builtin_amdgcn_mfma_f32_16x16x32_bf16(al, WXhi[kk], acc2, 0, 0, 0);
        }

        if (t > 1) {
            // ---- poll completion: re-load only still-unready chunks ----
            int bad = 0;
            #pragma unroll
            for (int i = 0; i < 8; ++i)
                bad |= (hv8[i] == POISON8 || hv8[i] == INIT8) ? (1 << i) : 0;
            while (bad) {
                #pragma unroll
                for (int i = 0; i < 8; ++i)
                    if (bad & (1 << i))
                        hv8[i] = __hip_atomic_load(src + tid + i * 256,
                                                   __ATOMIC_RELAXED, __HIP_MEMORY_SCOPE_AGENT);
                int nb = 0;
                #pragma unroll
                for (int i = 0; i < 8; ++i)
                    nb |= (hv8[i] == POISON8 || hv8[i] == INIT8) ? (1 << i) : 0;
                bad = nb;
            }
            #pragma unroll
            for (int i = 0; i < 8; ++i) {
                int idx = tid + i * 256, r = idx >> 7, c8 = idx & 127;
                *(u16x4*)&Hl[r][c8 * 4] = __builtin_bit_cast(u16x4, hv8[i]);
            }
        }

        // ---- poison own chunks of region (t+1)%3 (holds dead h_{t-2}).
        //      Safe: poll success above => peers' step-(t-1) reads done.
        //      Drained (vmcnt0) by a barrier below before our publish. ----
        if (tid < 64) {
            int rr = tid >> 2, cq = tid & 3;
            __hip_atomic_store(gbase + (size_t)((t + 1) % 3) * 2048
                                   + rr * 128 + (j0 >> 2) + cq,
                               (unsigned long long)POISON8,
                               __ATOMIC_RELAXED, __HIP_MEMORY_SCOPE_AGENT);
        }

        if (t > 1) {
            __syncthreads();   // Hl ready
            // ---- h part: h @ (Whi+Wlo) ----
            #pragma unroll
            for (int kk = 0; kk < 16; ++kk) {
                bf16x8 a = __builtin_bit_cast(bf16x8, *(const u16x8*)&Hl[n][kk * 32 + q * 8]);
                acc  = __builtin_amdgcn_mfma_f32_16x16x32_bf16(a, WHhi[kk], acc, 0, 0, 0);
                acc2 = __builtin_amdgcn_mfma_f32_16x16x32_bf16(a, WHlo[kk], acc2, 0, 0, 0);
            }
        }

        // ---- activations; D layout: row=(q*4+r)=batch, col=n=j ----
        #pragma unroll
        for (int r = 0; r < 4; ++r) {
            float zv  = acc[r] + acc2[r];
            float arg = (wav == 0) ? -2.f * zv : -zv;
            float s   = __builtin_amdgcn_rcpf(1.f + __expf(arg));
            float act = (wav == 0) ? (2.f * s - 1.f) : s;
            exch[wav][q * 4 + r][n] = act;
        }
        __syncthreads();   // exch ready; poison stores drained

        // ---- (b) wave-0: 4-cell update + immediate publish + out ----
        if (wav == 0) {
            float4 gv = *(const float4*)&exch[0][pb][pc * 4];
            float4 iv = *(const float4*)&exch[1][pb][pc * 4];
            float4 fv = *(const float4*)&exch[2][pb][pc * 4];
            float4 ov = *(const float4*)&exch[3][pb][pc * 4];
            float gg[4] = {gv.x, gv.y, gv.z, gv.w};
            float ii[4] = {iv.x, iv.y, iv.z, iv.w};
            float ff[4] = {fv.x, fv.y, fv.z, fv.w};
            float oo[4] = {ov.x, ov.y, ov.z, ov.w};
            float hv[4];
            u16x4 pk;
            #pragma unroll
            for (int e = 0; e < 4; ++e) {
                c4[e] = gg[e] * ii[e] + c4[e] * ff[e];
                float e2 = __expf(-2.f * c4[e]);
                float th = 2.f * __builtin_amdgcn_rcpf(1.f + e2) - 1.f;
                hv[e] = th * oo[e];
                pk[e] = f2bf(hv[e]);
            }
            if (t < Tn) {
                __hip_atomic_store(gbase + (size_t)(t % 3) * 2048
                                       + pb * 128 + (j0 >> 2) + pc,
                                   __builtin_bit_cast(unsigned long long, pk),
                                   __ATOMIC_RELAXED, __HIP_MEMORY_SCOPE_AGENT);
            }
            float4 o4; o4.x = hv[0]; o4.y = hv[1]; o4.z = hv[2]; o4.w = hv[3];
            *(float4*)(out + ((size_t)tau * Bn + b0 + pb) * Hn + j0 + pc * 4) = o4;
        }
        // waves 1-3 fall through to next-step staging; the staging barrier
        // re-syncs wave 0 (its publish tail hides under their staging).
    }
}

extern "C" void kernel_launch(void* const* d_in, const int* in_sizes, int n_in,
                              void* d_out, int out_size, void* d_ws, size_t ws_size,
                              hipStream_t stream) {
    // setup_inputs order: embeds, (w_gx,w_gh,bias_g), (w_ix,w_ih,bias_i),
    //                     (w_fx,w_fh,bias_f), (w_ox,w_oh,bias_o)
    lstm_persistent<<<dim3(NBLOCK), dim3(256), 0, stream>>>(
        (const float*)d_in[0],
        (const float*)d_in[1], (const float*)d_in[2], (const float*)d_in[3],
        (const float*)d_in[4], (const float*)d_in[5], (const float*)d_in[6],
        (const float*)d_in[7], (const float*)d_in[8], (const float*)d_in[9],
        (const float*)d_in[10], (const float*)d_in[11], (const float*)d_in[12],
        (float*)d_out, d_ws);
}

// Round 5
// 3637.455 us; speedup vs baseline: 1.2433x; 1.2433x over previous
//
#include <hip/hip_runtime.h>
#include <stdint.h>
#include <stddef.h>

// Persistent-LSTM, T=1024, B=64, E=H=512 (fp32 in/out).
//
// R6 = R4 skeleton (proven 3199us) + producer-tail cut. R5 post-mortem:
// early poll issue SAMPLES the region before peers publish (load value is
// captured at service time, not check time) => guaranteed retries, +41%.
// Reverted. Changes vs R4, consumer poll timing untouched:
//  (a) DISTRIBUTED IMMEDIATE PUBLISH: after the exch barrier, 64 publisher
//      threads (tid%4==0, 16 per wave) each read 4 gates as float4 from
//      exch, update 4 cells in regs, publish their one 8B chunk at once,
//      and do a coalesced float4 out store. Deletes hstage + one barrier;
//      h_t hits LLC ~300-500cy earlier => fewer consumer retries.
//  (b) HW bf16 casts in x staging (RNE, same numerics, less VALU).
//
// Exchange protocol (proven R3/R4):
//  - ws: [4 groups][3 regions][16][512] bf16 = 192KB. Region s%3 holds h_s.
//    8B chunks, relaxed agent-scope atomics, self-validating:
//      fresh := chunk != POISON8 (bf16 +inf x4, |h|<1) && != INIT8 (0xAA).
//  - Producer-side poison one region ahead after poll success; the exch
//    barrier (vmcnt drain) separates poison from publish.
//  - t==1 skips poll + h-MFMA (h_0=0); t==Tn skips publish.
//  - XCD-pair grouping: gid=(b>>1)&3, kid=((b>>3)<<1)|(b&1).
//
// Numerics: weights bf16 hi+lo in regs, x hi/lo split, h single bf16
// => absmax ~0.0039.

#define Tn 1024
#define Bn 64
#define Hn 512
#define En 512
#define NGROUP 4
#define NJBLK 32
#define NBLOCK (NGROUP * NJBLK)
#define POISON8 0x7F807F807F807F80ull
#define INIT8   0xAAAAAAAAAAAAAAAAull

using bf16x8 = __attribute__((ext_vector_type(8))) __bf16;
using f32x4  = __attribute__((ext_vector_type(4))) float;
using u16x8  = __attribute__((ext_vector_type(8))) unsigned short;
using u16x4  = __attribute__((ext_vector_type(4))) unsigned short;

__device__ __forceinline__ unsigned short f2bf(float f) {
    unsigned u = __builtin_bit_cast(unsigned, f);
    unsigned r = (u + 0x7FFFu + ((u >> 16) & 1u)) >> 16;
    return (unsigned short)r;
}
__device__ __forceinline__ float bf2f(unsigned short b) {
    unsigned u = ((unsigned)b) << 16;
    return __builtin_bit_cast(float, u);
}

__global__ __launch_bounds__(256, 1) void lstm_persistent(
    const float* __restrict__ embeds,
    const float* __restrict__ wx0, const float* __restrict__ wh0, const float* __restrict__ bs0,
    const float* __restrict__ wx1, const float* __restrict__ wh1, const float* __restrict__ bs1,
    const float* __restrict__ wx2, const float* __restrict__ wh2, const float* __restrict__ bs2,
    const float* __restrict__ wx3, const float* __restrict__ wh3, const float* __restrict__ bs3,
    float* __restrict__ out, void* __restrict__ ws)
{
    __shared__ unsigned short Xhi[16][520];            // x operand hi, +8 pad
    __shared__ unsigned short Xlo[16][520];            // x operand lo
    __shared__ unsigned short Hl[16][520];             // h operand (bf16)
    __shared__ __align__(16) float exch[4][16][20];    // gates; rows 16B-aligned

    const int tid  = threadIdx.x;
    const int wav  = tid >> 6;     // wave = gate (0=g,1=i,2=f,3=o)
    const int lane = tid & 63;
    const int q    = lane >> 4;
    const int n    = lane & 15;

    // XCD-pair grouping: XCD = blockIdx%8 (round-robin dispatch).
    const int bidx = blockIdx.x;
    const int gid  = (bidx >> 1) & 3;
    const int kid  = ((bidx >> 3) << 1) | (bidx & 1);
    const int b0   = gid * 16;
    const int j0   = kid * 16;

    // ws: [NGROUP][3][2048] qwords; region r holds h_s for s%3==r.
    unsigned long long* gbase = (unsigned long long*)ws + (size_t)gid * 3 * 2048;

    const float* wxp = (wav == 0) ? wx0 : (wav == 1) ? wx1 : (wav == 2) ? wx2 : wx3;
    const float* whp = (wav == 0) ? wh0 : (wav == 1) ? wh1 : (wav == 2) ? wh2 : wh3;
    const float* bsp = (wav == 0) ? bs0 : (wav == 1) ? bs1 : (wav == 2) ? bs2 : bs3;

    // ---- preload weight fragments into registers (bf16 hi/lo) ----
    // B-frag layout for mfma_f32_16x16x32_bf16: lane holds B[k=q*8+i][n]
    bf16x8 WXhi[16], WXlo[16], WHhi[16], WHlo[16];
    const int col = j0 + n;
    #pragma unroll
    for (int kk = 0; kk < 16; ++kk) {
        u16x8 xh, xl, hh, hl;
        #pragma unroll
        for (int i = 0; i < 8; ++i) {
            int k = kk * 32 + q * 8 + i;
            float w  = wxp[(size_t)k * Hn + col];
            unsigned short hi = f2bf(w);
            xh[i] = hi;
            xl[i] = f2bf(w - bf2f(hi));
            w  = whp[(size_t)k * Hn + col];
            hi = f2bf(w);
            hh[i] = hi;
            hl[i] = f2bf(w - bf2f(hi));
        }
        WXhi[kk] = __builtin_bit_cast(bf16x8, xh);
        WXlo[kk] = __builtin_bit_cast(bf16x8, xl);
        WHhi[kk] = __builtin_bit_cast(bf16x8, hh);
        WHlo[kk] = __builtin_bit_cast(bf16x8, hl);
    }
    const float bias_l = bsp[col];

    // publisher threads (tid%4==0): chunk pub = tid>>2 -> row rr, qword cq
    const int ispub = ((tid & 3) == 0);
    const int pub   = tid >> 2;
    const int rr    = pub >> 2, cq = pub & 3;
    float c4[4] = {0.f, 0.f, 0.f, 0.f};

    // ---- prologue: prefetch x_0 into registers ----
    float4 xpre[8];
    #pragma unroll
    for (int it = 0; it < 8; ++it) {
        int idx = tid + it * 256;
        int r = idx >> 7, cc = idx & 127;
        xpre[it] = ((const float4*)(embeds + ((size_t)(b0 + r)) * En))[cc];
    }

    for (int t = 1; t <= Tn; ++t) {
        const int tau = t - 1;

        // ---- stage x_tau: registers -> bf16 hi/lo in LDS ----
        #pragma unroll
        for (int it = 0; it < 8; ++it) {
            int idx = tid + it * 256;          // 0..2047
            int r = idx >> 7, cc = idx & 127;  // row(batch), float4 index
            float4 v = xpre[it];
            float fs[4] = {v.x, v.y, v.z, v.w};
            u16x4 vh, vl;
            #pragma unroll
            for (int e = 0; e < 4; ++e) {
                __bf16 hb = (__bf16)fs[e];                    // RNE
                vh[e] = __builtin_bit_cast(unsigned short, hb);
                vl[e] = __builtin_bit_cast(unsigned short,
                                           (__bf16)(fs[e] - (float)hb));
            }
            *(u16x4*)&Xhi[r][cc * 4] = vh;
            *(u16x4*)&Xlo[r][cc * 4] = vl;
        }
        __syncthreads();

        // ---- issue h-poll loads (R4 placement — do NOT move earlier) ----
        unsigned long long hv8[8];
        unsigned long long* src = gbase + (size_t)((t - 1) % 3) * 2048;
        if (t > 1) {
            #pragma unroll
            for (int i = 0; i < 8; ++i)
                hv8[i] = __hip_atomic_load(src + tid + i * 256,
                                           __ATOMIC_RELAXED, __HIP_MEMORY_SCOPE_AGENT);
        }

        // ---- prefetch x_t (next step) into registers ----
        if (t < Tn) {
            #pragma unroll
            for (int it = 0; it < 8; ++it) {
                int idx = tid + it * 256;
                int r = idx >> 7, cc = idx & 127;
                xpre[it] = ((const float4*)(embeds + ((size_t)t * Bn + b0 + r) * En))[cc];
            }
        }

        f32x4 acc, acc2;
        acc[0] = bias_l; acc[1] = bias_l; acc[2] = bias_l; acc[3] = bias_l;
        acc2[0] = 0.f; acc2[1] = 0.f; acc2[2] = 0.f; acc2[3] = 0.f;

        // ---- x part: (xhi+xlo) @ (Whi+Wlo), dropping lo*lo ----
        #pragma unroll
        for (int kk = 0; kk < 16; ++kk) {
            bf16x8 ah = __builtin_bit_cast(bf16x8, *(const u16x8*)&Xhi[n][kk * 32 + q * 8]);
            bf16x8 al = __builtin_bit_cast(bf16x8, *(const u16x8*)&Xlo[n][kk * 32 + q * 8]);
            acc  = __builtin_amdgcn_mfma_f32_16x16x32_bf16(ah, WXhi[kk], acc, 0, 0, 0);
            acc2 = __builtin_amdgcn_mfma_f32_16x16x32_bf16(ah, WXlo[kk], acc2, 0, 0, 0);
            acc2 = __builtin_amdgcn_mfma_f32_16x16x32_bf16(al, WXhi[kk], acc2, 0, 0, 0);
        }

        if (t > 1) {
            // ---- poll completion: re-load only still-unready chunks ----
            int bad = 0;
            #pragma unroll
            for (int i = 0; i < 8; ++i)
                bad |= (hv8[i] == POISON8 || hv8[i] == INIT8) ? (1 << i) : 0;
            while (bad) {
                #pragma unroll
                for (int i = 0; i < 8; ++i)
                    if (bad & (1 << i))
                        hv8[i] = __hip_atomic_load(src + tid + i * 256,
                                                   __ATOMIC_RELAXED, __HIP_MEMORY_SCOPE_AGENT);
                int nb = 0;
                #pragma unroll
                for (int i = 0; i < 8; ++i)
                    nb |= (hv8[i] == POISON8 || hv8[i] == INIT8) ? (1 << i) : 0;
                bad = nb;
            }
            #pragma unroll
            for (int i = 0; i < 8; ++i) {
                int idx = tid + i * 256, r = idx >> 7, c8 = idx & 127;
                *(u16x4*)&Hl[r][c8 * 4] = __builtin_bit_cast(u16x4, hv8[i]);
            }
        }

        // ---- poison own chunks of region (t+1)%3 (holds dead h_{t-2}).
        //      Safe: poll success above => peers' step-(t-1) reads done.
        //      Drained (vmcnt0) by the exch barrier before our publish. ----
        if (tid < 64) {
            int pr = tid >> 2, pq = tid & 3;
            __hip_atomic_store(gbase + (size_t)((t + 1) % 3) * 2048
                                   + pr * 128 + (j0 >> 2) + pq,
                               (unsigned long long)POISON8,
                               __ATOMIC_RELAXED, __HIP_MEMORY_SCOPE_AGENT);
        }

        if (t > 1) {
            __syncthreads();   // Hl ready
            // ---- h part: h @ (Whi+Wlo) ----
            #pragma unroll
            for (int kk = 0; kk < 16; ++kk) {
                bf16x8 a = __builtin_bit_cast(bf16x8, *(const u16x8*)&Hl[n][kk * 32 + q * 8]);
                acc  = __builtin_amdgcn_mfma_f32_16x16x32_bf16(a, WHhi[kk], acc, 0, 0, 0);
                acc2 = __builtin_amdgcn_mfma_f32_16x16x32_bf16(a, WHlo[kk], acc2, 0, 0, 0);
            }
        }

        // ---- activations; D layout: row=(q*4+r)=batch, col=n=j ----
        #pragma unroll
        for (int r = 0; r < 4; ++r) {
            float zv  = acc[r] + acc2[r];
            float arg = (wav == 0) ? -2.f * zv : -zv;
            float s   = __builtin_amdgcn_rcpf(1.f + __expf(arg));
            float act = (wav == 0) ? (2.f * s - 1.f) : s;
            exch[wav][q * 4 + r][n] = act;
        }
        __syncthreads();   // exch ready; poison stores drained

        // ---- distributed publishers: 4-cell update + immediate publish ----
        if (ispub) {
            float4 gv = *(const float4*)&exch[0][rr][cq * 4];
            float4 iv = *(const float4*)&exch[1][rr][cq * 4];
            float4 fv = *(const float4*)&exch[2][rr][cq * 4];
            float4 ov = *(const float4*)&exch[3][rr][cq * 4];
            float gg[4] = {gv.x, gv.y, gv.z, gv.w};
            float ii[4] = {iv.x, iv.y, iv.z, iv.w};
            float ff[4] = {fv.x, fv.y, fv.z, fv.w};
            float oo[4] = {ov.x, ov.y, ov.z, ov.w};
            float hv[4];
            u16x4 pk;
            #pragma unroll
            for (int e = 0; e < 4; ++e) {
                c4[e] = gg[e] * ii[e] + c4[e] * ff[e];
                float e2 = __expf(-2.f * c4[e]);
                float th = 2.f * __builtin_amdgcn_rcpf(1.f + e2) - 1.f;
                hv[e] = th * oo[e];
                pk[e] = f2bf(hv[e]);
            }
            if (t < Tn) {
                __hip_atomic_store(gbase + (size_t)(t % 3) * 2048
                                       + rr * 128 + (j0 >> 2) + cq,
                                   __builtin_bit_cast(unsigned long long, pk),
                                   __ATOMIC_RELAXED, __HIP_MEMORY_SCOPE_AGENT);
            }
            float4 o4; o4.x = hv[0]; o4.y = hv[1]; o4.z = hv[2]; o4.w = hv[3];
            *(float4*)(out + ((size_t)tau * Bn + b0 + rr) * Hn + j0 + cq * 4) = o4;
        }
        // non-publishers fall through to next-step staging; the staging
        // barrier re-syncs (publish tail hides under their staging).
    }
}

extern "C" void kernel_launch(void* const* d_in, const int* in_sizes, int n_in,
                              void* d_out, int out_size, void* d_ws, size_t ws_size,
                              hipStream_t stream) {
    // setup_inputs order: embeds, (w_gx,w_gh,bias_g), (w_ix,w_ih,bias_i),
    //                     (w_fx,w_fh,bias_f), (w_ox,w_oh,bias_o)
    lstm_persistent<<<dim3(NBLOCK), dim3(256), 0, stream>>>(
        (const float*)d_in[0],
        (const float*)d_in[1], (const float*)d_in[2], (const float*)d_in[3],
        (const float*)d_in[4], (const float*)d_in[5], (const float*)d_in[6],
        (const float*)d_in[7], (const float*)d_in[8], (const float*)d_in[9],
        (const float*)d_in[10], (const float*)d_in[11], (const float*)d_in[12],
        (float*)d_out, d_ws);
}

// Round 6
// 3229.539 us; speedup vs baseline: 1.4003x; 1.1263x over previous
//
#include <hip/hip_runtime.h>
#include <stdint.h>
#include <stddef.h>

// Persistent-LSTM, T=1024, B=64, E=H=512 (fp32 in/out).
//
// R7 = R4 skeleton (proven 3199us; R5/R6 tail experiments both regressed and
// are reverted) + two strictly chain-shortening changes:
//  (a) SHUFFLE-PACK PUBLISH: cell update stays 256-wide parallel (R4-exact);
//      the 4 lanes holding one 8B chunk (same b, j=4c..4c+3) are adjacent
//      lanes of one wave => 3x __shfl_down packs the chunk in lane 4c, which
//      publishes directly. Deletes hstage LDS + barrier #4; publish issues
//      ~250-400cy earlier => more poll slack for consumers, fewer retries.
//  (b) ACC SPLIT: x-part now uses 3 independent accumulators (acc,acc2,acc3)
//      so the per-kk MFMA chains are 16 deep instead of 32; summed in the
//      activation epilogue. Pure register arithmetic.
//
// Exchange protocol (proven R3/R4):
//  - ws: [4 groups][3 regions][16][512] bf16 = 192KB. Region s%3 holds h_s.
//    8B chunks, relaxed agent-scope atomics, self-validating:
//      fresh := chunk != POISON8 (bf16 +inf x4, |h|<1) && != INIT8 (0xAA).
//  - Producer-side poison one region ahead after poll success; drained by
//    the Hl/exch barriers (vmcnt0) before any same-chunk republish at t+1.
//  - t==1 skips poll + h-MFMA (h_0=0); t==Tn skips publish.
//  - XCD-pair grouping: gid=(b>>1)&3, kid=((b>>3)<<1)|(b&1).
//  - Poll loads issued AFTER the staging barrier (R4 placement — R5 proved
//    earlier issue samples before peers publish and guarantees retries).
//
// Numerics: weights bf16 hi+lo in regs, x hi/lo split, h single bf16
// => absmax ~0.0039.

#define Tn 1024
#define Bn 64
#define Hn 512
#define En 512
#define NGROUP 4
#define NJBLK 32
#define NBLOCK (NGROUP * NJBLK)
#define POISON8 0x7F807F807F807F80ull
#define INIT8   0xAAAAAAAAAAAAAAAAull

using bf16x8 = __attribute__((ext_vector_type(8))) __bf16;
using f32x4  = __attribute__((ext_vector_type(4))) float;
using u16x8  = __attribute__((ext_vector_type(8))) unsigned short;
using u16x4  = __attribute__((ext_vector_type(4))) unsigned short;

__device__ __forceinline__ unsigned short f2bf(float f) {
    unsigned u = __builtin_bit_cast(unsigned, f);
    unsigned r = (u + 0x7FFFu + ((u >> 16) & 1u)) >> 16;
    return (unsigned short)r;
}
__device__ __forceinline__ float bf2f(unsigned short b) {
    unsigned u = ((unsigned)b) << 16;
    return __builtin_bit_cast(float, u);
}

__global__ __launch_bounds__(256, 1) void lstm_persistent(
    const float* __restrict__ embeds,
    const float* __restrict__ wx0, const float* __restrict__ wh0, const float* __restrict__ bs0,
    const float* __restrict__ wx1, const float* __restrict__ wh1, const float* __restrict__ bs1,
    const float* __restrict__ wx2, const float* __restrict__ wh2, const float* __restrict__ bs2,
    const float* __restrict__ wx3, const float* __restrict__ wh3, const float* __restrict__ bs3,
    float* __restrict__ out, void* __restrict__ ws)
{
    __shared__ unsigned short Xhi[16][520];   // x operand hi, +8 pad
    __shared__ unsigned short Xlo[16][520];   // x operand lo
    __shared__ unsigned short Hl[16][520];    // h operand (bf16)
    __shared__ float exch[4][16][17];         // gate exchange g/i/f/o

    const int tid  = threadIdx.x;
    const int wav  = tid >> 6;     // wave = gate (0=g,1=i,2=f,3=o)
    const int lane = tid & 63;
    const int q    = lane >> 4;
    const int n    = lane & 15;

    // XCD-pair grouping: XCD = blockIdx%8 (round-robin dispatch).
    const int bidx = blockIdx.x;
    const int gid  = (bidx >> 1) & 3;
    const int kid  = ((bidx >> 3) << 1) | (bidx & 1);
    const int b0   = gid * 16;
    const int j0   = kid * 16;

    // ws: [NGROUP][3][2048] qwords; region r holds h_s for s%3==r.
    unsigned long long* gbase = (unsigned long long*)ws + (size_t)gid * 3 * 2048;

    const float* wxp = (wav == 0) ? wx0 : (wav == 1) ? wx1 : (wav == 2) ? wx2 : wx3;
    const float* whp = (wav == 0) ? wh0 : (wav == 1) ? wh1 : (wav == 2) ? wh2 : wh3;
    const float* bsp = (wav == 0) ? bs0 : (wav == 1) ? bs1 : (wav == 2) ? bs2 : bs3;

    // ---- preload weight fragments into registers (bf16 hi/lo) ----
    // B-frag layout for mfma_f32_16x16x32_bf16: lane holds B[k=q*8+i][n]
    bf16x8 WXhi[16], WXlo[16], WHhi[16], WHlo[16];
    const int col = j0 + n;
    #pragma unroll
    for (int kk = 0; kk < 16; ++kk) {
        u16x8 xh, xl, hh, hl;
        #pragma unroll
        for (int i = 0; i < 8; ++i) {
            int k = kk * 32 + q * 8 + i;
            float w  = wxp[(size_t)k * Hn + col];
            unsigned short hi = f2bf(w);
            xh[i] = hi;
            xl[i] = f2bf(w - bf2f(hi));
            w  = whp[(size_t)k * Hn + col];
            hi = f2bf(w);
            hh[i] = hi;
            hl[i] = f2bf(w - bf2f(hi));
        }
        WXhi[kk] = __builtin_bit_cast(bf16x8, xh);
        WXlo[kk] = __builtin_bit_cast(bf16x8, xl);
        WHhi[kk] = __builtin_bit_cast(bf16x8, hh);
        WHlo[kk] = __builtin_bit_cast(bf16x8, hl);
    }
    const float bias_l = bsp[col];
    float c_state = 0.f;   // thread owns (b,j) = (tid>>4, tid&15)
    const int b = tid >> 4, j = tid & 15;

    // ---- prologue: prefetch x_0 into registers ----
    float4 xpre[8];
    #pragma unroll
    for (int it = 0; it < 8; ++it) {
        int idx = tid + it * 256;
        int r = idx >> 7, cc = idx & 127;
        xpre[it] = ((const float4*)(embeds + ((size_t)(b0 + r)) * En))[cc];
    }

    for (int t = 1; t <= Tn; ++t) {
        const int tau = t - 1;

        // ---- stage x_tau: registers -> bf16 hi/lo in LDS ----
        #pragma unroll
        for (int it = 0; it < 8; ++it) {
            int idx = tid + it * 256;          // 0..2047
            int r = idx >> 7, cc = idx & 127;  // row(batch), float4 index
            float4 v = xpre[it];
            float fs[4] = {v.x, v.y, v.z, v.w};
            u16x4 vh, vl;
            #pragma unroll
            for (int e = 0; e < 4; ++e) {
                unsigned short hb = f2bf(fs[e]);
                vh[e] = hb;
                vl[e] = f2bf(fs[e] - bf2f(hb));
            }
            *(u16x4*)&Xhi[r][cc * 4] = vh;
            *(u16x4*)&Xlo[r][cc * 4] = vl;
        }
        __syncthreads();

        // ---- issue h-poll loads (R4 placement — do NOT move earlier) ----
        unsigned long long hv8[8];
        unsigned long long* src = gbase + (size_t)((t - 1) % 3) * 2048;
        if (t > 1) {
            #pragma unroll
            for (int i = 0; i < 8; ++i)
                hv8[i] = __hip_atomic_load(src + tid + i * 256,
                                           __ATOMIC_RELAXED, __HIP_MEMORY_SCOPE_AGENT);
        }

        // ---- prefetch x_t (next step) into registers ----
        if (t < Tn) {
            #pragma unroll
            for (int it = 0; it < 8; ++it) {
                int idx = tid + it * 256;
                int r = idx >> 7, cc = idx & 127;
                xpre[it] = ((const float4*)(embeds + ((size_t)t * Bn + b0 + r) * En))[cc];
            }
        }

        f32x4 acc, acc2, acc3;
        acc[0] = bias_l; acc[1] = bias_l; acc[2] = bias_l; acc[3] = bias_l;
        acc2[0] = 0.f; acc2[1] = 0.f; acc2[2] = 0.f; acc2[3] = 0.f;
        acc3[0] = 0.f; acc3[1] = 0.f; acc3[2] = 0.f; acc3[3] = 0.f;

        // ---- x part: 3 independent 16-deep MFMA chains ----
        #pragma unroll
        for (int kk = 0; kk < 16; ++kk) {
            bf16x8 ah = __builtin_bit_cast(bf16x8, *(const u16x8*)&Xhi[n][kk * 32 + q * 8]);
            bf16x8 al = __builtin_bit_cast(bf16x8, *(const u16x8*)&Xlo[n][kk * 32 + q * 8]);
            acc  = __builtin_amdgcn_mfma_f32_16x16x32_bf16(ah, WXhi[kk], acc, 0, 0, 0);
            acc2 = __builtin_amdgcn_mfma_f32_16x16x32_bf16(ah, WXlo[kk], acc2, 0, 0, 0);
            acc3 = __builtin_amdgcn_mfma_f32_16x16x32_bf16(al, WXhi[kk], acc3, 0, 0, 0);
        }

        if (t > 1) {
            // ---- poll completion: re-load only still-unready chunks ----
            int bad = 0;
            #pragma unroll
            for (int i = 0; i < 8; ++i)
                bad |= (hv8[i] == POISON8 || hv8[i] == INIT8) ? (1 << i) : 0;
            while (bad) {
                #pragma unroll
                for (int i = 0; i < 8; ++i)
                    if (bad & (1 << i))
                        hv8[i] = __hip_atomic_load(src + tid + i * 256,
                                                   __ATOMIC_RELAXED, __HIP_MEMORY_SCOPE_AGENT);
                int nb = 0;
                #pragma unroll
                for (int i = 0; i < 8; ++i)
                    nb |= (hv8[i] == POISON8 || hv8[i] == INIT8) ? (1 << i) : 0;
                bad = nb;
            }
            #pragma unroll
            for (int i = 0; i < 8; ++i) {
                int idx = tid + i * 256, r = idx >> 7, c8 = idx & 127;
                *(u16x4*)&Hl[r][c8 * 4] = __builtin_bit_cast(u16x4, hv8[i]);
            }
        }

        // ---- poison own chunks of region (t+1)%3 (holds dead h_{t-2}).
        //      Safe: poll success above => peers' step-(t-1) reads done.
        //      Drained (vmcnt0) by the barriers below before republish. ----
        if (tid < 64) {
            int pr = tid >> 2, pq = tid & 3;
            __hip_atomic_store(gbase + (size_t)((t + 1) % 3) * 2048
                                   + pr * 128 + (j0 >> 2) + pq,
                               (unsigned long long)POISON8,
                               __ATOMIC_RELAXED, __HIP_MEMORY_SCOPE_AGENT);
        }

        if (t > 1) {
            __syncthreads();   // Hl ready
            // ---- h part: h @ (Whi+Wlo) ----
            #pragma unroll
            for (int kk = 0; kk < 16; ++kk) {
                bf16x8 a = __builtin_bit_cast(bf16x8, *(const u16x8*)&Hl[n][kk * 32 + q * 8]);
                acc  = __builtin_amdgcn_mfma_f32_16x16x32_bf16(a, WHhi[kk], acc, 0, 0, 0);
                acc2 = __builtin_amdgcn_mfma_f32_16x16x32_bf16(a, WHlo[kk], acc2, 0, 0, 0);
            }
        }

        // ---- activations; D layout: row=(q*4+r)=batch, col=n=j ----
        #pragma unroll
        for (int r = 0; r < 4; ++r) {
            float zv  = acc[r] + acc2[r] + acc3[r];
            float arg = (wav == 0) ? -2.f * zv : -zv;
            float s   = __builtin_amdgcn_rcpf(1.f + __expf(arg));
            float act = (wav == 0) ? (2.f * s - 1.f) : s;
            exch[wav][q * 4 + r][n] = act;
        }
        __syncthreads();   // exch ready; poison stores drained

        // ---- per-thread cell update (R4-exact, 256-wide parallel) ----
        float hv;
        {
            float g  = exch[0][b][j];
            float ig = exch[1][b][j];
            float fg = exch[2][b][j];
            float og = exch[3][b][j];
            c_state = g * ig + c_state * fg;
            float e2 = __expf(-2.f * c_state);
            float th = 2.f * __builtin_amdgcn_rcpf(1.f + e2) - 1.f;
            hv = th * og;
        }

        // ---- shuffle-pack publish: lanes 4c..4c+3 hold (b, j=4c..4c+3);
        //      pack in lane 4c, publish one 8B chunk per 4 lanes ----
        {
            unsigned pk = (unsigned)f2bf(hv);
            unsigned v1 = __shfl_down((int)pk, 1);
            unsigned v2 = __shfl_down((int)pk, 2);
            unsigned v3 = __shfl_down((int)pk, 3);
            if ((lane & 3) == 0 && t < Tn) {
                unsigned long long qv =
                    (unsigned long long)(pk | (v1 << 16))
                    | ((unsigned long long)(v2 | (v3 << 16)) << 32);
                __hip_atomic_store(gbase + (size_t)(t % 3) * 2048
                                       + b * 128 + (j0 >> 2) + (j >> 2),
                                   qv, __ATOMIC_RELAXED, __HIP_MEMORY_SCOPE_AGENT);
            }
        }

        // ---- output store (fire-and-forget, after publish) ----
        out[((size_t)tau * Bn + b0 + b) * Hn + j0 + j] = hv;
    }
}

extern "C" void kernel_launch(void* const* d_in, const int* in_sizes, int n_in,
                              void* d_out, int out_size, void* d_ws, size_t ws_size,
                              hipStream_t stream) {
    // setup_inputs order: embeds, (w_gx,w_gh,bias_g), (w_ix,w_ih,bias_i),
    //                     (w_fx,w_fh,bias_f), (w_ox,w_oh,bias_o)
    lstm_persistent<<<dim3(NBLOCK), dim3(256), 0, stream>>>(
        (const float*)d_in[0],
        (const float*)d_in[1], (const float*)d_in[2], (const float*)d_in[3],
        (const float*)d_in[4], (const float*)d_in[5], (const float*)d_in[6],
        (const float*)d_in[7], (const float*)d_in[8], (const float*)d_in[9],
        (const float*)d_in[10], (const float*)d_in[11], (const float*)d_in[12],
        (float*)d_out, d_ws);
}